// Round 3
// baseline (207.677 us; speedup 1.0000x reference)
//
#include <hip/hip_runtime.h>
#include <stdint.h>

// y[b,s,m] = sum_n x[b,s,n] * W[m,n] + bias[m], W from TT cores (bf16, built once).
// Pipeline: build_w (8 MB bf16) -> fused 8-phase 256^2 GEMM (A = fp32 X,
// converted to bf16 in-kernel during reg-staging; B = bf16 W via global_load_lds).

typedef __attribute__((ext_vector_type(8))) __bf16 bf16x8;
typedef __attribute__((ext_vector_type(4))) float f32x4;
typedef __attribute__((ext_vector_type(8))) unsigned short us8;

#define M_TOT 16384
#define N_TOT 2048
#define K_TOT 2048

__device__ __forceinline__ unsigned short f2bf(float f) {
  union { float f; unsigned u; } v; v.f = f;
  unsigned u = v.u;
  u += 0x7FFFu + ((u >> 16) & 1u);   // RNE
  return (unsigned short)(u >> 16);
}

__device__ __forceinline__ void gld_lds16(const void* g, void* l) {
  __builtin_amdgcn_global_load_lds(
      (const __attribute__((address_space(1))) unsigned int*)g,
      (__attribute__((address_space(3))) unsigned int*)l, 16, 0, 0);
}

#define BARRIER() __builtin_amdgcn_s_barrier()
#define WAIT_LGKM0() asm volatile("s_waitcnt lgkmcnt(0)" ::: "memory")
#define WAIT_VM0() asm volatile("s_waitcnt vmcnt(0)" ::: "memory")
#define WAIT_VM4() asm volatile("s_waitcnt vmcnt(4)" ::: "memory")
#define WAIT_VM6() asm volatile("s_waitcnt vmcnt(6)" ::: "memory")
#define WAIT_VM8() asm volatile("s_waitcnt vmcnt(8)" ::: "memory")

// ---------------------------------------------------------------------------
// Kernel 1: reconstruct W (bf16). W[n,k], n=out (2048), k=in (2048).
// ---------------------------------------------------------------------------
__global__ void build_w_kernel(const float* __restrict__ c1,
                               const float* __restrict__ c2,
                               unsigned short* __restrict__ W) {
  int idx = blockIdx.x * 256 + threadIdx.x;      // n*2048 + k
  int k = idx & (K_TOT - 1);
  int n = idx >> 11;
  int i = n >> 9, ob = n & 511;
  int m1 = ob >> 4, m2 = ob & 15;
  int j = k >> 9, ib = k & 511;
  int n1 = ib >> 4, n2 = ib & 15;
  const float* a = c1 + ((((i * 4 + j) * 32 + m1) * 32 + n1) * 16);
  const float* b = c2 + ((i * 4 + j) * 4096 + m2 * 16 + n2);
  float s = 0.f;
#pragma unroll
  for (int r = 0; r < 16; ++r) s += a[r] * b[r * 256];
  W[idx] = f2bf(s);
}

// ---------------------------------------------------------------------------
// Kernel 2: fused 8-phase 256x256 GEMM, BK=64, 512 thr (8 waves 2Mx4N).
// LDS 128 KiB: [buf2][sect4][128x64 bf16]; sect 0/1 = A halves, 2/3 = B halves.
// A: fp32 global -> VGPR (issued 2 phases early) -> cvt bf16 -> swizzled
//    ds_write_b128 (blk ^= row&7).  B: gload_lds with inverse-swizzled source.
// vmcnt counted (6/4), never 0 in steady state.
// ---------------------------------------------------------------------------
__global__ __launch_bounds__(512, 2) void gemm_fused_kernel(
    const float* __restrict__ X, const unsigned short* __restrict__ W,
    const float* __restrict__ bias, float* __restrict__ Y) {
  __shared__ __align__(16) unsigned short lds[2][4][128 * 64];

  const int tid = threadIdx.x;
  const int lane = tid & 63;
  const int wid = tid >> 6;
  const int wm = wid >> 2, wn = wid & 3;     // 2 x 4 wave grid

  // bijective XCD swizzle: 512 wgs, 8 XCDs, 64-wg chunks; 8 consecutive wgs
  // of a chunk share an mblk (A panel stays hot in the XCD's L2).
  const int bid = blockIdx.x;
  const int xcd = bid & 7, loc = bid >> 3;
  const int mblk = xcd * 8 + (loc >> 3);     // 0..63
  const int nblk = loc & 7;                  // 0..7
  const int m0 = mblk * 256, n0 = nblk * 256;

  // fragment read addressing
  const int fr = lane & 15, g = lane >> 4;
  const int swz = fr & 7;
  const int blkB0 = ((0 + g) ^ swz) * 16;    // ksub=0 byte offset of 16B block
  const int blkB1 = ((4 + g) ^ swz) * 16;    // ksub=1
  const int arow = fr * 128;                 // + m*2048 bytes
  const int brow = ((wn & 1) * 64 + fr) * 128;  // + n*2048 bytes

  // staging thread mapping: row-within-64 = tid>>3, 8-col block = tid&7
  const int sr = tid >> 3;
  const int b8 = tid & 7;
  const int scB = (b8 ^ (sr & 7)) * 8;       // B: inverse-swizzled global col
  const int ldsAoff = (b8 ^ (sr & 7)) * 8;   // A: swizzled LDS col (shorts)

  auto stageB = [&](int half, int buf, int kt) {
    const unsigned short* base = W + (size_t)(n0 + half * 128) * K_TOT + kt * 64 + scB;
#pragma unroll
    for (int i = 0; i < 2; ++i)
      gld_lds16(base + (size_t)(i * 64 + sr) * K_TOT,
                &lds[buf][2 + half][i * 4096 + wid * 512]);
  };

  f32x4 apre[2][4];  // [half][i*2+v]
  auto loadA = [&](int half, int kt) {
    const float* base = X + (size_t)(m0 + half * 128 + sr) * K_TOT + kt * 64 + b8 * 8;
#pragma unroll
    for (int i = 0; i < 2; ++i) {
      apre[half][i * 2 + 0] = *(const f32x4*)(base + (size_t)i * 64 * K_TOT);
      apre[half][i * 2 + 1] = *(const f32x4*)(base + (size_t)i * 64 * K_TOT + 4);
    }
  };
  auto writeA = [&](int half, int buf) {
#pragma unroll
    for (int i = 0; i < 2; ++i) {
      us8 h;
#pragma unroll
      for (int v = 0; v < 4; ++v) {
        h[v]     = f2bf(apre[half][i * 2 + 0][v]);
        h[4 + v] = f2bf(apre[half][i * 2 + 1][v]);
      }
      *(us8*)&lds[buf][half][(i * 64 + sr) * 64 + ldsAoff] = h;
    }
  };

  auto ldA = [&](int c, int m, int ks) -> bf16x8 {
    const char* p = (const char*)&lds[c][wm][0] + arow + m * 2048 + (ks ? blkB1 : blkB0);
    return *(const bf16x8*)p;
  };
  auto ldB = [&](int c, int n, int ks) -> bf16x8 {
    const char* p = (const char*)&lds[c][2 + (wn >> 1)][0] + brow + n * 2048 + (ks ? blkB1 : blkB0);
    return *(const bf16x8*)p;
  };

  f32x4 acc[8][4];
#pragma unroll
  for (int m = 0; m < 8; ++m)
#pragma unroll
    for (int n = 0; n < 4; ++n) acc[m][n] = {0.f, 0.f, 0.f, 0.f};

  const int NT = K_TOT / 64;  // 32 K-tiles

  // prologue: A(0) reg->cvt->LDS; B(0)->buf0, B(1)->buf1 via gload_lds
  loadA(0, 0); loadA(1, 0);                       // 8 vm loads
  stageB(0, 0, 0); stageB(1, 0, 0);
  stageB(0, 1, 1); stageB(1, 1, 1);               // 8 vm loads
  WAIT_VM8();                                     // A regs ready
  writeA(0, 0); writeA(1, 0);
  WAIT_VM0();                                     // B(0), B(1) landed
  WAIT_LGKM0();                                   // A writes visible
  BARRIER();

  bf16x8 bq[4][2];
  for (int t = 0; t < NT; ++t) {
    const int c = t & 1;
#pragma unroll
    for (int q = 0; q < 4; ++q) {
      // --- ds reads for this phase's MFMA quadrant ---
      bf16x8 a0 = ldA(c, 2 * q, 0);
      bf16x8 a0k = ldA(c, 2 * q, 1);
      bf16x8 a1 = ldA(c, 2 * q + 1, 0);
      bf16x8 a1k = ldA(c, 2 * q + 1, 1);
      if (q == 0) {
#pragma unroll
        for (int n = 0; n < 4; ++n) {
          bq[n][0] = ldB(c, n, 0);
          bq[n][1] = ldB(c, n, 1);
        }
      }
      // --- staging work for this phase ---
      if (q == 0 && t + 1 < NT) loadA(0, t + 1);       // issue early (T14)
      if (q == 1 && t + 1 < NT) loadA(1, t + 1);
      if (q == 2) {
        if (t + 2 < NT) stageB(0, c, t + 2);
        if (t + 1 < NT) {
          if (t + 2 < NT) WAIT_VM6(); else WAIT_VM4();  // drain A half0 (+old B)
          writeA(0, c ^ 1);
        }
      }
      if (q == 3) {
        if (t + 2 < NT) stageB(1, c, t + 2);
        if (t + 1 < NT) {
          if (t + 2 < NT) WAIT_VM4(); else WAIT_VM0();  // drain A half1
          writeA(1, c ^ 1);
        }
      }
      BARRIER();
      WAIT_LGKM0();   // frag reads done; also drains our ds_writes pre-barrier
      __builtin_amdgcn_s_setprio(1);
#pragma unroll
      for (int n = 0; n < 4; ++n) {
        acc[2 * q][n] = __builtin_amdgcn_mfma_f32_16x16x32_bf16(a0, bq[n][0], acc[2 * q][n], 0, 0, 0);
        acc[2 * q][n] = __builtin_amdgcn_mfma_f32_16x16x32_bf16(a0k, bq[n][1], acc[2 * q][n], 0, 0, 0);
        acc[2 * q + 1][n] = __builtin_amdgcn_mfma_f32_16x16x32_bf16(a1, bq[n][0], acc[2 * q + 1][n], 0, 0, 0);
        acc[2 * q + 1][n] = __builtin_amdgcn_mfma_f32_16x16x32_bf16(a1k, bq[n][1], acc[2 * q + 1][n], 0, 0, 0);
      }
      __builtin_amdgcn_s_setprio(0);
      BARRIER();
    }
  }

  // epilogue: D layout col=lane&15, row=(lane>>4)*4+j  [verified]
  const int rb4 = g * 4;
#pragma unroll
  for (int n = 0; n < 4; ++n) {
    const int gc = n0 + wn * 64 + n * 16 + fr;
    const float bv = bias[gc];
#pragma unroll
    for (int m = 0; m < 8; ++m) {
#pragma unroll
      for (int j = 0; j < 4; ++j) {
        const int gr = m0 + wm * 128 + m * 16 + rb4 + j;
        Y[(size_t)gr * N_TOT + gc] = acc[m][n][j] + bv;
      }
    }
  }
}

extern "C" void kernel_launch(void* const* d_in, const int* in_sizes, int n_in,
                              void* d_out, int out_size, void* d_ws, size_t ws_size,
                              hipStream_t stream) {
  const float* x    = (const float*)d_in[0];
  const float* c1   = (const float*)d_in[1];
  const float* c2   = (const float*)d_in[2];
  const float* bias = (const float*)d_in[3];
  float* y          = (float*)d_out;
  unsigned short* W = (unsigned short*)d_ws;   // 2048*2048 bf16 = 8 MB

  build_w_kernel<<<(N_TOT * K_TOT) / 256, 256, 0, stream>>>(c1, c2, W);
  gemm_fused_kernel<<<(M_TOT / 256) * (N_TOT / 256), 512, 0, stream>>>(x, W, bias, y);
}